// Round 1
// baseline (913.736 us; speedup 1.0000x reference)
//
#include <hip/hip_runtime.h>
#include <cstdio>
#include <cstdint>

typedef _Float16 h8 __attribute__((ext_vector_type(8)));
typedef _Float16 h4 __attribute__((ext_vector_type(4)));
typedef _Float16 h2 __attribute__((ext_vector_type(2)));
typedef float f4 __attribute__((ext_vector_type(4)));

#define GLD16(g, l) __builtin_amdgcn_global_load_lds( \
    (const __attribute__((address_space(1))) void*)(g), \
    (__attribute__((address_space(3))) void*)(l), 16, 0, 0)

static constexpr int HOUT = 28;
static constexpr long long NSP = 64LL * HOUT * HOUT;     // 50176 output pixels
static constexpr long long NEL = NSP * 256;              // 12,845,056 output elems

// ---------------------------------------------------------------------------
// init: zero the atomic-max slots and the zero page (re-done every launch)
__global__ void init_ws(int* __restrict__ gmax, _Float16* __restrict__ zp)
{
    const int t = threadIdx.x;
    if (t < 3) gmax[t] = 0;
    for (int i = t; i < 512; i += 256) zp[i] = (_Float16)0.f;
}

// ---------------------------------------------------------------------------
// weight prep: per-output-channel symmetric 8-bit quant, BN fold, k-reorder.
// conv1 weights are written channel-DUPLICATED (k = p*256 + cc, cc=ci or ci+128)
// to match the hi/lo split input.
__global__ void prep_w1(const float* __restrict__ w1, const float* __restrict__ g1,
                        const float* __restrict__ b1, const float* __restrict__ m1,
                        const float* __restrict__ v1, const float* __restrict__ asp,
                        _Float16* __restrict__ wq, float* __restrict__ scale1,
                        float* __restrict__ bias1)
{
    const int o = blockIdx.x, t = threadIdx.x;
    const float f = g1[o] * rsqrtf(v1[o] + 1e-5f);
    const float* wr = w1 + (size_t)o * 1152;
    float amax = 0.f;
    for (int i = t; i < 1152; i += 256) amax = fmaxf(amax, fabsf(wr[i] * f));
    __shared__ float red[256];
    red[t] = amax; __syncthreads();
    for (int s = 128; s > 0; s >>= 1) { if (t < s) red[t] = fmaxf(red[t], red[t + s]); __syncthreads(); }
    const float ws = fmaxf(red[0] / 127.f, 1e-8f);
    for (int idx = t; idx < 2304; idx += 256) {
        int p = idx >> 8, cc = idx & 255, ci = cc & 127;
        float q = fminf(fmaxf(rintf(wr[ci * 9 + p] * f / ws), -128.f), 127.f);
        wq[(size_t)o * 2304 + idx] = (_Float16)q;
    }
    if (t == 0) {
        const float bs = ws * asp[0];
        const float bf = b1[o] - m1[o] * f;
        float bq = fminf(fmaxf(rintf(bf / bs), -128.f), 127.f);
        scale1[o] = bs;
        bias1[o] = bq * bs;
    }
}

__global__ void prep_w2(const float* __restrict__ w2, const float* __restrict__ g2,
                        const float* __restrict__ b2, const float* __restrict__ m2,
                        const float* __restrict__ v2,
                        _Float16* __restrict__ wq, float* __restrict__ ws2,
                        float* __restrict__ b2f)
{
    const int o = blockIdx.x, t = threadIdx.x;
    const float f = g2[o] * rsqrtf(v2[o] + 1e-5f);
    const float* wr = w2 + (size_t)o * 2304;
    float amax = 0.f;
    for (int i = t; i < 2304; i += 256) amax = fmaxf(amax, fabsf(wr[i] * f));
    __shared__ float red[256];
    red[t] = amax; __syncthreads();
    for (int s = 128; s > 0; s >>= 1) { if (t < s) red[t] = fmaxf(red[t], red[t + s]); __syncthreads(); }
    const float ws = fmaxf(red[0] / 127.f, 1e-8f);
    for (int idx = t; idx < 2304; idx += 256) {
        int p = idx >> 8, ci = idx & 255;
        float q = fminf(fmaxf(rintf(wr[ci * 9 + p] * f / ws), -128.f), 127.f);
        wq[(size_t)o * 2304 + idx] = (_Float16)q;
    }
    if (t == 0) { ws2[o] = ws; b2f[o] = b2[o] - m2[o] * f; }
}

__global__ void prep_wsc(const float* __restrict__ wsc, const float* __restrict__ asp,
                         _Float16* __restrict__ wq, float* __restrict__ scale_sc)
{
    const int o = blockIdx.x, t = threadIdx.x;
    const float* wr = wsc + (size_t)o * 128;
    float amax = (t < 128) ? fabsf(wr[t]) : 0.f;
    __shared__ float red[256];
    red[t] = amax; __syncthreads();
    for (int s = 128; s > 0; s >>= 1) { if (t < s) red[t] = fmaxf(red[t], red[t + s]); __syncthreads(); }
    const float ws = fmaxf(red[0] / 127.f, 1e-8f);
    float q = fminf(fmaxf(rintf(wr[t & 127] / ws), -128.f), 127.f);
    wq[(size_t)o * 256 + t] = (_Float16)q;   // duplicated layout [o][256]
    if (t == 0) scale_sc[o] = ws * asp[0];
}

// ---------------------------------------------------------------------------
// x (NCHW f32) -> NHWC fp16 hi/lo pairs of x/act_scale. one block per (b,h).
__global__ void prep_x(const float* __restrict__ x, const float* __restrict__ asp,
                       _Float16* __restrict__ xf)
{
    const int b = blockIdx.x / 56, h = blockIdx.x - (blockIdx.x / 56) * 56;
    const float as = asp[0];
    __shared__ float tile[56 * 129];
    const float* src = x + ((size_t)b * 128 * 56 + h) * 56;   // x[b][c][h][w]
    for (int i = threadIdx.x; i < 7168; i += 256) {
        int c = i / 56, ww = i - c * 56;
        tile[ww * 129 + c] = src[(size_t)c * 3136 + ww] / as;
    }
    __syncthreads();
    _Float16* dst = xf + (size_t)(b * 56 + h) * 56 * 256;     // [b][h][w][256]
    for (int j = threadIdx.x; j < 7168; j += 256) {           // pairs of halves
        int ww = j >> 7, q = j & 127;
        int cc = q * 2;
        int c0 = cc & 127, c1 = (cc + 1) & 127;
        float x0 = tile[ww * 129 + c0];
        float x1 = tile[ww * 129 + c1];
        h2 o;
        if (cc < 128) { o[0] = (_Float16)x0; o[1] = (_Float16)x1; }
        else {
            _Float16 h0 = (_Float16)x0, h1 = (_Float16)x1;
            o[0] = (_Float16)(x0 - (float)h0);
            o[1] = (_Float16)(x1 - (float)h1);
        }
        *(h2*)&dst[(size_t)j * 2] = o;
    }
}

// ---------------------------------------------------------------------------
// implicit-GEMM conv (m97 structure): BM=BN=128, BK=32, 4 waves, f16 MFMA.
// M=Cout=256, N=50176 spatial, K=9*256. SC fuses the 1x1-s2 shortcut at p==4.
template<int HINP, int WINP, int STRIDE, bool SC>
__global__ __launch_bounds__(256, 2)
void conv_k(const _Float16* __restrict__ Xf,     // NHWC [64][HINP][WINP][256]
            const _Float16* __restrict__ Wq,     // [256][2304]
            const _Float16* __restrict__ Wsc,    // [256][256] (dup) or null
            const float* __restrict__ scale,
            const float* __restrict__ bias,
            const float* __restrict__ scale_sc,
            float* __restrict__ Y,               // [N][256] post-relu
            float* __restrict__ Ysc,             // [N][256] shortcut (no relu)
            int* __restrict__ gmax,
            const _Float16* __restrict__ zp)
{
    constexpr int KT = 2304;
    __shared__ __attribute__((aligned(16))) _Float16 As[4096];
    __shared__ __attribute__((aligned(16))) _Float16 Bs[4096];
    __shared__ float wred[4];

    const int t = threadIdx.x;
    const int wave = t >> 6, lane = t & 63;
    const int wm = wave >> 1, wn = wave & 1;
    const int fr = lane & 15, fq = lane >> 4;
    const int m0 = blockIdx.y << 7;
    const int n0 = blockIdx.x << 7;
    const int chunk = t & 3;
    const int rowt = t >> 2;

    int bb[2], oh[2], ow[2];
#pragma unroll
    for (int i = 0; i < 2; ++i) {
        int n = n0 + i * 64 + rowt;
        bb[i] = n / (HOUT * HOUT);
        int r = n - bb[i] * (HOUT * HOUT);
        oh[i] = r / HOUT;
        ow[i] = r - oh[i] * HOUT;
    }

    const char* Ab = (const char*)Wq + ((size_t)m0 * KT + (size_t)chunk * 8) * 2;
    size_t aoff[2];
#pragma unroll
    for (int i = 0; i < 2; ++i) aoff[i] = (size_t)(i * 64 + rowt) * (KT * 2);

    f4 acc[4][4];
    f4 accs[4][4];
#pragma unroll
    for (int i = 0; i < 4; ++i)
#pragma unroll
        for (int j = 0; j < 4; ++j) {
            acc[i][j] = f4{0.f, 0.f, 0.f, 0.f};
            if constexpr (SC) accs[i][j] = f4{0.f, 0.f, 0.f, 0.f};
        }

#pragma unroll 1
    for (int p = 0; p < 9; ++p) {
        const int kh = p / 3, kw = p - kh * 3;
        const char* bsrc[2];
#pragma unroll
        for (int i = 0; i < 2; ++i) {
            int ih = oh[i] * STRIDE - 1 + kh;
            int iw = ow[i] * STRIDE - 1 + kw;
            bool ok = ((unsigned)ih < (unsigned)HINP) && ((unsigned)iw < (unsigned)WINP);
            bsrc[i] = ok ? (const char*)Xf + ((((size_t)bb[i] * HINP + ih) * WINP + iw) * 256 + (size_t)chunk * 8) * 2
                         : (const char*)zp + (size_t)chunk * 16;
        }
        const char* ap = Ab + (size_t)p * 512;
#pragma unroll 1
        for (int kc = 0; kc < 8; ++kc) {
#pragma unroll
            for (int i = 0; i < 2; ++i) {
                GLD16(ap + aoff[i] + kc * 64, (char*)As + i * 4096 + wave * 1024);
                GLD16(bsrc[i] + kc * 64,      (char*)Bs + i * 4096 + wave * 1024);
            }
            __syncthreads();
            h8 af[4], bf[4];
#pragma unroll
            for (int x = 0; x < 4; ++x) {
                af[x] = *(const h8*)&As[(wm * 64 + x * 16 + fr) * 32 + fq * 8];
                bf[x] = *(const h8*)&Bs[(wn * 64 + x * 16 + fr) * 32 + fq * 8];
            }
#pragma unroll
            for (int mi = 0; mi < 4; ++mi)
#pragma unroll
                for (int ni = 0; ni < 4; ++ni)
                    acc[mi][ni] = __builtin_amdgcn_mfma_f32_16x16x32_f16(af[mi], bf[ni], acc[mi][ni], 0, 0, 0);
            if constexpr (SC) {
                if (p == 4) {
                    h8 sf[4];
#pragma unroll
                    for (int mi = 0; mi < 4; ++mi)
                        sf[mi] = *(const h8*)&Wsc[(size_t)(m0 + wm * 64 + mi * 16 + fr) * 256 + kc * 32 + fq * 8];
#pragma unroll
                    for (int mi = 0; mi < 4; ++mi)
#pragma unroll
                        for (int ni = 0; ni < 4; ++ni)
                            accs[mi][ni] = __builtin_amdgcn_mfma_f32_16x16x32_f16(sf[mi], bf[ni], accs[mi][ni], 0, 0, 0);
                }
            }
            __syncthreads();
        }
    }

    float tmax = 0.f;
#pragma unroll
    for (int mi = 0; mi < 4; ++mi) {
        const int m = m0 + wm * 64 + mi * 16 + fq * 4;
        const f4 sc = *(const f4*)&scale[m];
        const f4 bi = *(const f4*)&bias[m];
        f4 ssc;
        if constexpr (SC) ssc = *(const f4*)&scale_sc[m];
#pragma unroll
        for (int ni = 0; ni < 4; ++ni) {
            const int n = n0 + wn * 64 + ni * 16 + fr;
            f4 v = acc[mi][ni] * sc + bi;
            f4 r;
            r.x = fmaxf(v.x, 0.f); r.y = fmaxf(v.y, 0.f);
            r.z = fmaxf(v.z, 0.f); r.w = fmaxf(v.w, 0.f);
            tmax = fmaxf(tmax, fmaxf(fmaxf(r.x, r.y), fmaxf(r.z, r.w)));
            *(f4*)&Y[(size_t)n * 256 + m] = r;
            if constexpr (SC) {
                f4 s = accs[mi][ni] * ssc;
                *(f4*)&Ysc[(size_t)n * 256 + m] = s;
            }
        }
    }
#pragma unroll
    for (int off = 32; off > 0; off >>= 1)
        tmax = fmaxf(tmax, __shfl_xor(tmax, off));
    if (lane == 0) wred[wave] = tmax;
    __syncthreads();
    if (t == 0) {
        float mx = fmaxf(fmaxf(wred[0], wred[1]), fmaxf(wred[2], wred[3]));
        atomicMax(gmax, __float_as_int(mx));
    }
}

// ---------------------------------------------------------------------------
__global__ void mid_k(const int* __restrict__ gmax, const float* __restrict__ ws2,
                      const float* __restrict__ b2f, float* __restrict__ scale2,
                      float* __restrict__ bias2, float* __restrict__ a1p)
{
    const int o = threadIdx.x;
    const float a1 = fmaxf(__int_as_float(gmax[0]) / 1023.f, 1e-8f);
    const float s2 = ws2[o] * a1;
    float bq = fminf(fmaxf(rintf(b2f[o] / s2), -128.f), 127.f);
    scale2[o] = s2;
    bias2[o] = bq * s2;
    if (o == 0) a1p[0] = a1;
}

__global__ void quant_x2(const float* __restrict__ t1, const float* __restrict__ a1p,
                         _Float16* __restrict__ x2)
{
    const size_t i = (size_t)blockIdx.x * 256 + threadIdx.x;
    const float a1 = a1p[0];
    f4 v = ((const f4*)t1)[i];
    h4 o;
    o[0] = (_Float16)fminf(rintf(v.x / a1), 1023.f);
    o[1] = (_Float16)fminf(rintf(v.y / a1), 1023.f);
    o[2] = (_Float16)fminf(rintf(v.z / a1), 1023.f);
    o[3] = (_Float16)fminf(rintf(v.w / a1), 1023.f);
    ((h4*)x2)[i] = o;
}

__global__ void add_short_k(const float* __restrict__ t2, const float* __restrict__ sh,
                            int* __restrict__ gmax, float* __restrict__ o3)
{
    const size_t i = (size_t)blockIdx.x * 256 + threadIdx.x;
    const float a2 = fmaxf(__int_as_float(gmax[1]) / 1023.f, 1e-8f);
    f4 v = ((const f4*)t2)[i];
    f4 s = ((const f4*)sh)[i];
    f4 r;
    r.x = fmaxf(fminf(rintf(v.x / a2), 1023.f) * a2 + s.x, 0.f);
    r.y = fmaxf(fminf(rintf(v.y / a2), 1023.f) * a2 + s.y, 0.f);
    r.z = fmaxf(fminf(rintf(v.z / a2), 1023.f) * a2 + s.z, 0.f);
    r.w = fmaxf(fminf(rintf(v.w / a2), 1023.f) * a2 + s.w, 0.f);
    ((f4*)o3)[i] = r;
    float tmax = fmaxf(fmaxf(r.x, r.y), fmaxf(r.z, r.w));
#pragma unroll
    for (int off = 32; off > 0; off >>= 1)
        tmax = fmaxf(tmax, __shfl_xor(tmax, off));
    if ((threadIdx.x & 63) == 0) atomicMax(gmax + 2, __float_as_int(tmax));
}

// final requant + NHWC->NCHW transpose; one block per (b, oh)
__global__ void finalize_k(const float* __restrict__ o3, const int* __restrict__ gmax,
                           float* __restrict__ dout, int out_size)
{
    const int b = blockIdx.x / 28, oh = blockIdx.x - (blockIdx.x / 28) * 28;
    const float a3 = fmaxf(__int_as_float(gmax[2]) / 1023.f, 1e-8f);
    __shared__ float tile[28 * 257];
    const float* src = o3 + (size_t)(b * 28 + oh) * 28 * 256;
    for (int i = threadIdx.x; i < 7168; i += 256)
        tile[(i >> 8) * 257 + (i & 255)] = src[i];
    __syncthreads();
    for (int j = threadIdx.x; j < 7168; j += 256) {
        int c = j / 28, ww = j - (j / 28) * 28;
        float v = tile[ww * 257 + c];
        float q = fminf(rintf(v / a3), 1023.f);
        dout[(((size_t)b * 256 + c) * 28 + oh) * 28 + ww] = q * a3;
    }
    if (blockIdx.x == 0 && threadIdx.x == 0) dout[(size_t)out_size - 1] = a3;
}

// ---------------------------------------------------------------------------
extern "C" void kernel_launch(void* const* d_in, const int* in_sizes, int n_in,
                              void* d_out, int out_size, void* d_ws, size_t ws_size,
                              hipStream_t stream)
{
    const float* x   = (const float*)d_in[0];
    const float* as_ = (const float*)d_in[1];
    const float* wsc = (const float*)d_in[2];
    const float* w1  = (const float*)d_in[3];
    const float* g1  = (const float*)d_in[4];
    const float* b1  = (const float*)d_in[5];
    const float* m1  = (const float*)d_in[6];
    const float* v1  = (const float*)d_in[7];
    const float* w2  = (const float*)d_in[8];
    const float* g2  = (const float*)d_in[9];
    const float* b2  = (const float*)d_in[10];
    const float* m2  = (const float*)d_in[11];
    const float* v2  = (const float*)d_in[12];
    float* out = (float*)d_out;

    char* w = (char*)d_ws;
    size_t off = 0;
    auto alloc = [&](size_t bytes) { size_t c = off; off += (bytes + 255) & ~(size_t)255; return c; };
    const size_t oXF = alloc((size_t)64 * 56 * 56 * 256 * 2);  // hi/lo NHWC fp16 (102.8MB)
    const size_t oY1 = alloc((size_t)NEL * 4);                 // t1 / out3 (51.4MB)
    const size_t oSH = alloc((size_t)NEL * 4);                 // shortcut (51.4MB)
    const size_t oX2 = alloc((size_t)NEL * 2);                 // x2 fp16 (25.7MB)
    const size_t oW1 = alloc((size_t)256 * 2304 * 2);
    const size_t oW2 = alloc((size_t)256 * 2304 * 2);
    const size_t oWS = alloc((size_t)256 * 256 * 2);
    const size_t oSC = alloc((size_t)8 * 256 * 4);
    const size_t oMS = alloc(4096);
    if (off > ws_size) {
        fprintf(stderr, "kernel_launch: ws too small: need %zu have %zu\n", off, ws_size);
        return;
    }

    _Float16* xf   = (_Float16*)(w + oXF);
    float*    y1   = (float*)(w + oY1);
    float*    sh   = (float*)(w + oSH);
    _Float16* x2   = (_Float16*)(w + oX2);
    _Float16* wq1  = (_Float16*)(w + oW1);
    _Float16* wq2  = (_Float16*)(w + oW2);
    _Float16* wscd = (_Float16*)(w + oWS);
    float* scl = (float*)(w + oSC);
    float *scale1 = scl, *bias1 = scl + 256, *scale_sc = scl + 512, *ws2 = scl + 768,
          *b2f = scl + 1024, *scale2 = scl + 1280, *bias2 = scl + 1536, *a1p = scl + 1792;
    int* gmax = (int*)(w + oMS);
    _Float16* zp = (_Float16*)(w + oMS + 1024);
    float* y2 = (float*)(w + oXF);   // reuse xf region (dead after conv1)
    float* o3 = (float*)(w + oY1);   // reuse t1 region (dead after quant_x2)

    init_ws<<<1, 256, 0, stream>>>(gmax, zp);
    prep_wsc<<<256, 256, 0, stream>>>(wsc, as_, wscd, scale_sc);
    prep_w1<<<256, 256, 0, stream>>>(w1, g1, b1, m1, v1, as_, wq1, scale1, bias1);
    prep_w2<<<256, 256, 0, stream>>>(w2, g2, b2, m2, v2, wq2, ws2, b2f);
    prep_x<<<64 * 56, 256, 0, stream>>>(x, as_, xf);
    conv_k<56, 56, 2, true><<<dim3(392, 2), 256, 0, stream>>>(
        xf, wq1, wscd, scale1, bias1, scale_sc, y1, sh, gmax + 0, zp);
    mid_k<<<1, 256, 0, stream>>>(gmax, ws2, b2f, scale2, bias2, a1p);
    quant_x2<<<12544, 256, 0, stream>>>(y1, a1p, x2);
    conv_k<28, 28, 1, false><<<dim3(392, 2), 256, 0, stream>>>(
        x2, wq2, nullptr, scale2, bias2, nullptr, y2, nullptr, gmax + 1, zp);
    add_short_k<<<12544, 256, 0, stream>>>(y2, sh, gmax, o3);
    finalize_k<<<64 * 28, 256, 0, stream>>>(o3, gmax, out, out_size);
}

// Round 2
// 362.331 us; speedup vs baseline: 2.5218x; 2.5218x over previous
//
#include <hip/hip_runtime.h>
#include <cstdio>
#include <cstdint>

typedef _Float16 h8 __attribute__((ext_vector_type(8)));
typedef _Float16 h4 __attribute__((ext_vector_type(4)));
typedef _Float16 h2 __attribute__((ext_vector_type(2)));
typedef float f4 __attribute__((ext_vector_type(4)));

#define GLD16(g, l) __builtin_amdgcn_global_load_lds( \
    (const __attribute__((address_space(1))) void*)(g), \
    (__attribute__((address_space(3))) void*)(l), 16, 0, 0)

static constexpr int HOUT = 28;
static constexpr long long NSP = 64LL * HOUT * HOUT;     // 50176 output pixels
static constexpr long long NEL = NSP * 256;              // 12,845,056 output elems
static constexpr int NSLOT = 64;                         // spread atomic slots
static constexpr int SLOTSTRIDE = 32;                    // 128B apart

// ---------------------------------------------------------------------------
// init: zero the spread atomic-max slots and the zero page (every launch)
__global__ void init_ws(int* __restrict__ slots, _Float16* __restrict__ zp)
{
    const int t = threadIdx.x;
    for (int i = t; i < 3 * NSLOT * SLOTSTRIDE; i += 256) slots[i] = 0;
    for (int i = t; i < 512; i += 256) zp[i] = (_Float16)0.f;
}

__device__ __forceinline__ float slot_max(const int* __restrict__ slots)
{
    float m = 0.f;
#pragma unroll
    for (int i = 0; i < NSLOT; ++i) m = fmaxf(m, __int_as_float(slots[i * SLOTSTRIDE]));
    return m;
}

// ---------------------------------------------------------------------------
// weight prep: per-output-channel symmetric 8-bit quant, BN fold, k-reorder.
// conv1 weights are written channel-DUPLICATED (k = p*256 + cc, cc=ci or ci+128)
// to match the hi/lo split input.
__global__ void prep_w1(const float* __restrict__ w1, const float* __restrict__ g1,
                        const float* __restrict__ b1, const float* __restrict__ m1,
                        const float* __restrict__ v1, const float* __restrict__ asp,
                        _Float16* __restrict__ wq, float* __restrict__ scale1,
                        float* __restrict__ bias1)
{
    const int o = blockIdx.x, t = threadIdx.x;
    const float f = g1[o] * rsqrtf(v1[o] + 1e-5f);
    const float* wr = w1 + (size_t)o * 1152;
    float amax = 0.f;
    for (int i = t; i < 1152; i += 256) amax = fmaxf(amax, fabsf(wr[i] * f));
    __shared__ float red[256];
    red[t] = amax; __syncthreads();
    for (int s = 128; s > 0; s >>= 1) { if (t < s) red[t] = fmaxf(red[t], red[t + s]); __syncthreads(); }
    const float ws = fmaxf(red[0] / 127.f, 1e-8f);
    for (int idx = t; idx < 2304; idx += 256) {
        int p = idx >> 8, cc = idx & 255, ci = cc & 127;
        float q = fminf(fmaxf(rintf(wr[ci * 9 + p] * f / ws), -128.f), 127.f);
        wq[(size_t)o * 2304 + idx] = (_Float16)q;
    }
    if (t == 0) {
        const float bs = ws * asp[0];
        const float bf = b1[o] - m1[o] * f;
        float bq = fminf(fmaxf(rintf(bf / bs), -128.f), 127.f);
        scale1[o] = bs;
        bias1[o] = bq * bs;
    }
}

__global__ void prep_w2(const float* __restrict__ w2, const float* __restrict__ g2,
                        const float* __restrict__ b2, const float* __restrict__ m2,
                        const float* __restrict__ v2,
                        _Float16* __restrict__ wq, float* __restrict__ ws2,
                        float* __restrict__ b2f)
{
    const int o = blockIdx.x, t = threadIdx.x;
    const float f = g2[o] * rsqrtf(v2[o] + 1e-5f);
    const float* wr = w2 + (size_t)o * 2304;
    float amax = 0.f;
    for (int i = t; i < 2304; i += 256) amax = fmaxf(amax, fabsf(wr[i] * f));
    __shared__ float red[256];
    red[t] = amax; __syncthreads();
    for (int s = 128; s > 0; s >>= 1) { if (t < s) red[t] = fmaxf(red[t], red[t + s]); __syncthreads(); }
    const float ws = fmaxf(red[0] / 127.f, 1e-8f);
    for (int idx = t; idx < 2304; idx += 256) {
        int p = idx >> 8, ci = idx & 255;
        float q = fminf(fmaxf(rintf(wr[ci * 9 + p] * f / ws), -128.f), 127.f);
        wq[(size_t)o * 2304 + idx] = (_Float16)q;
    }
    if (t == 0) { ws2[o] = ws; b2f[o] = b2[o] - m2[o] * f; }
}

__global__ void prep_wsc(const float* __restrict__ wsc, const float* __restrict__ asp,
                         _Float16* __restrict__ wq, float* __restrict__ scale_sc)
{
    const int o = blockIdx.x, t = threadIdx.x;
    const float* wr = wsc + (size_t)o * 128;
    float amax = (t < 128) ? fabsf(wr[t]) : 0.f;
    __shared__ float red[256];
    red[t] = amax; __syncthreads();
    for (int s = 128; s > 0; s >>= 1) { if (t < s) red[t] = fmaxf(red[t], red[t + s]); __syncthreads(); }
    const float ws = fmaxf(red[0] / 127.f, 1e-8f);
    float q = fminf(fmaxf(rintf(wr[t & 127] / ws), -128.f), 127.f);
    wq[(size_t)o * 256 + t] = (_Float16)q;   // duplicated layout [o][256]
    if (t == 0) scale_sc[o] = ws * asp[0];
}

// ---------------------------------------------------------------------------
// x (NCHW f32) -> NHWC fp16 hi/lo pairs of x/act_scale. one block per (b,h).
__global__ void prep_x(const float* __restrict__ x, const float* __restrict__ asp,
                       _Float16* __restrict__ xf)
{
    const int b = blockIdx.x / 56, h = blockIdx.x - (blockIdx.x / 56) * 56;
    const float as = asp[0];
    __shared__ float tile[56 * 129];
    const float* src = x + ((size_t)b * 128 * 56 + h) * 56;   // x[b][c][h][w]
    for (int i = threadIdx.x; i < 7168; i += 256) {
        int c = i / 56, ww = i - c * 56;
        tile[ww * 129 + c] = src[(size_t)c * 3136 + ww] / as;
    }
    __syncthreads();
    _Float16* dst = xf + (size_t)(b * 56 + h) * 56 * 256;     // [b][h][w][256]
    for (int j = threadIdx.x; j < 7168; j += 256) {           // pairs of halves
        int ww = j >> 7, q = j & 127;
        int cc = q * 2;
        int c0 = cc & 127, c1 = (cc + 1) & 127;
        float x0 = tile[ww * 129 + c0];
        float x1 = tile[ww * 129 + c1];
        h2 o;
        if (cc < 128) { o[0] = (_Float16)x0; o[1] = (_Float16)x1; }
        else {
            _Float16 h0 = (_Float16)x0, h1 = (_Float16)x1;
            o[0] = (_Float16)(x0 - (float)h0);
            o[1] = (_Float16)(x1 - (float)h1);
        }
        *(h2*)&dst[(size_t)j * 2] = o;
    }
}

// ---------------------------------------------------------------------------
// implicit-GEMM conv (m97 structure): BM=BN=128, BK=32, 4 waves, f16 MFMA.
// M=Cout=256, N=50176 spatial, K=9*256. SC fuses the 1x1-s2 shortcut at p==4.
template<int HINP, int WINP, int STRIDE, bool SC>
__global__ __launch_bounds__(256, 2)
void conv_k(const _Float16* __restrict__ Xf,     // NHWC [64][HINP][WINP][256]
            const _Float16* __restrict__ Wq,     // [256][2304]
            const _Float16* __restrict__ Wsc,    // [256][256] (dup) or null
            const float* __restrict__ scale,
            const float* __restrict__ bias,
            const float* __restrict__ scale_sc,
            float* __restrict__ Y,               // [N][256] post-relu
            float* __restrict__ Ysc,             // [N][256] shortcut (no relu)
            int* __restrict__ slots,             // spread max slots
            const _Float16* __restrict__ zp)
{
    constexpr int KT = 2304;
    __shared__ __attribute__((aligned(16))) _Float16 As[4096];
    __shared__ __attribute__((aligned(16))) _Float16 Bs[4096];
    __shared__ float wred[4];

    const int t = threadIdx.x;
    const int wave = t >> 6, lane = t & 63;
    const int wm = wave >> 1, wn = wave & 1;
    const int fr = lane & 15, fq = lane >> 4;
    const int m0 = blockIdx.y << 7;
    const int n0 = blockIdx.x << 7;
    const int chunk = t & 3;
    const int rowt = t >> 2;

    int bb[2], oh[2], ow[2];
#pragma unroll
    for (int i = 0; i < 2; ++i) {
        int n = n0 + i * 64 + rowt;
        bb[i] = n / (HOUT * HOUT);
        int r = n - bb[i] * (HOUT * HOUT);
        oh[i] = r / HOUT;
        ow[i] = r - oh[i] * HOUT;
    }

    const char* Ab = (const char*)Wq + ((size_t)m0 * KT + (size_t)chunk * 8) * 2;
    size_t aoff[2];
#pragma unroll
    for (int i = 0; i < 2; ++i) aoff[i] = (size_t)(i * 64 + rowt) * (KT * 2);

    f4 acc[4][4];
    f4 accs[4][4];
#pragma unroll
    for (int i = 0; i < 4; ++i)
#pragma unroll
        for (int j = 0; j < 4; ++j) {
            acc[i][j] = f4{0.f, 0.f, 0.f, 0.f};
            if constexpr (SC) accs[i][j] = f4{0.f, 0.f, 0.f, 0.f};
        }

#pragma unroll 1
    for (int p = 0; p < 9; ++p) {
        const int kh = p / 3, kw = p - kh * 3;
        const char* bsrc[2];
#pragma unroll
        for (int i = 0; i < 2; ++i) {
            int ih = oh[i] * STRIDE - 1 + kh;
            int iw = ow[i] * STRIDE - 1 + kw;
            bool ok = ((unsigned)ih < (unsigned)HINP) && ((unsigned)iw < (unsigned)WINP);
            bsrc[i] = ok ? (const char*)Xf + ((((size_t)bb[i] * HINP + ih) * WINP + iw) * 256 + (size_t)chunk * 8) * 2
                         : (const char*)zp + (size_t)chunk * 16;
        }
        const char* ap = Ab + (size_t)p * 512;
#pragma unroll 1
        for (int kc = 0; kc < 8; ++kc) {
#pragma unroll
            for (int i = 0; i < 2; ++i) {
                GLD16(ap + aoff[i] + kc * 64, (char*)As + i * 4096 + wave * 1024);
                GLD16(bsrc[i] + kc * 64,      (char*)Bs + i * 4096 + wave * 1024);
            }
            __syncthreads();
            h8 af[4], bf[4];
#pragma unroll
            for (int x = 0; x < 4; ++x) {
                af[x] = *(const h8*)&As[(wm * 64 + x * 16 + fr) * 32 + fq * 8];
                bf[x] = *(const h8*)&Bs[(wn * 64 + x * 16 + fr) * 32 + fq * 8];
            }
#pragma unroll
            for (int mi = 0; mi < 4; ++mi)
#pragma unroll
                for (int ni = 0; ni < 4; ++ni)
                    acc[mi][ni] = __builtin_amdgcn_mfma_f32_16x16x32_f16(af[mi], bf[ni], acc[mi][ni], 0, 0, 0);
            if constexpr (SC) {
                if (p == 4) {
                    h8 sf[4];
#pragma unroll
                    for (int mi = 0; mi < 4; ++mi)
                        sf[mi] = *(const h8*)&Wsc[(size_t)(m0 + wm * 64 + mi * 16 + fr) * 256 + kc * 32 + fq * 8];
#pragma unroll
                    for (int mi = 0; mi < 4; ++mi)
#pragma unroll
                        for (int ni = 0; ni < 4; ++ni)
                            accs[mi][ni] = __builtin_amdgcn_mfma_f32_16x16x32_f16(sf[mi], bf[ni], accs[mi][ni], 0, 0, 0);
                }
            }
            __syncthreads();
        }
    }

    float tmax = 0.f;
#pragma unroll
    for (int mi = 0; mi < 4; ++mi) {
        const int m = m0 + wm * 64 + mi * 16 + fq * 4;
        const f4 sc = *(const f4*)&scale[m];
        const f4 bi = *(const f4*)&bias[m];
        f4 ssc;
        if constexpr (SC) ssc = *(const f4*)&scale_sc[m];
#pragma unroll
        for (int ni = 0; ni < 4; ++ni) {
            const int n = n0 + wn * 64 + ni * 16 + fr;
            f4 v = acc[mi][ni] * sc + bi;
            f4 r;
            r.x = fmaxf(v.x, 0.f); r.y = fmaxf(v.y, 0.f);
            r.z = fmaxf(v.z, 0.f); r.w = fmaxf(v.w, 0.f);
            tmax = fmaxf(tmax, fmaxf(fmaxf(r.x, r.y), fmaxf(r.z, r.w)));
            *(f4*)&Y[(size_t)n * 256 + m] = r;
            if constexpr (SC) {
                f4 s = accs[mi][ni] * ssc;
                *(f4*)&Ysc[(size_t)n * 256 + m] = s;
            }
        }
    }
#pragma unroll
    for (int off = 32; off > 0; off >>= 1)
        tmax = fmaxf(tmax, __shfl_xor(tmax, off));
    if (lane == 0) wred[wave] = tmax;
    __syncthreads();
    if (t == 0) {
        float mx = fmaxf(fmaxf(wred[0], wred[1]), fmaxf(wred[2], wred[3]));
        atomicMax(&slots[((blockIdx.x + blockIdx.y * 392) & (NSLOT - 1)) * SLOTSTRIDE],
                  __float_as_int(mx));
    }
}

// ---------------------------------------------------------------------------
__global__ void mid_k(const int* __restrict__ slotsA, const float* __restrict__ ws2,
                      const float* __restrict__ b2f, float* __restrict__ scale2,
                      float* __restrict__ bias2, float* __restrict__ a1p)
{
    const int o = threadIdx.x;
    const float a1 = fmaxf(slot_max(slotsA) / 1023.f, 1e-8f);
    const float s2 = ws2[o] * a1;
    float bq = fminf(fmaxf(rintf(b2f[o] / s2), -128.f), 127.f);
    scale2[o] = s2;
    bias2[o] = bq * s2;
    if (o == 0) a1p[0] = a1;
}

__global__ void quant_x2(const float* __restrict__ t1, const float* __restrict__ a1p,
                         _Float16* __restrict__ x2)
{
    const size_t i = (size_t)blockIdx.x * 256 + threadIdx.x;
    const float a1 = a1p[0];
    f4 v = ((const f4*)t1)[i];
    h4 o;
    o[0] = (_Float16)fminf(rintf(v.x / a1), 1023.f);
    o[1] = (_Float16)fminf(rintf(v.y / a1), 1023.f);
    o[2] = (_Float16)fminf(rintf(v.z / a1), 1023.f);
    o[3] = (_Float16)fminf(rintf(v.w / a1), 1023.f);
    ((h4*)x2)[i] = o;
}

// requant t2, add shortcut, relu; per-block reduce + spread-slot atomic.
// grid: 3136 blocks x 256 threads x 4 f4 each (grid-strided).
__global__ void add_short_k(const float* __restrict__ t2, const float* __restrict__ sh,
                            const int* __restrict__ slotsB, int* __restrict__ slotsC,
                            float* __restrict__ o3)
{
    const float a2 = fmaxf(slot_max(slotsB) / 1023.f, 1e-8f);
    const float inv_a2 = 1.f / a2;
    float tmax = 0.f;
    const size_t base = (size_t)blockIdx.x * 256 + threadIdx.x;
#pragma unroll
    for (int it = 0; it < 4; ++it) {
        const size_t i = base + (size_t)it * 802816;   // 3136*256
        f4 v = ((const f4*)t2)[i];
        f4 s = ((const f4*)sh)[i];
        f4 r;
        r.x = fmaxf(fminf(rintf(v.x * inv_a2), 1023.f) * a2 + s.x, 0.f);
        r.y = fmaxf(fminf(rintf(v.y * inv_a2), 1023.f) * a2 + s.y, 0.f);
        r.z = fmaxf(fminf(rintf(v.z * inv_a2), 1023.f) * a2 + s.z, 0.f);
        r.w = fmaxf(fminf(rintf(v.w * inv_a2), 1023.f) * a2 + s.w, 0.f);
        ((f4*)o3)[i] = r;
        tmax = fmaxf(tmax, fmaxf(fmaxf(r.x, r.y), fmaxf(r.z, r.w)));
    }
#pragma unroll
    for (int off = 32; off > 0; off >>= 1)
        tmax = fmaxf(tmax, __shfl_xor(tmax, off));
    __shared__ float wred[4];
    if ((threadIdx.x & 63) == 0) wred[threadIdx.x >> 6] = tmax;
    __syncthreads();
    if (threadIdx.x == 0) {
        float mx = fmaxf(fmaxf(wred[0], wred[1]), fmaxf(wred[2], wred[3]));
        atomicMax(&slotsC[(blockIdx.x & (NSLOT - 1)) * SLOTSTRIDE], __float_as_int(mx));
    }
}

// final requant + NHWC->NCHW transpose; one block per (b, oh)
__global__ void finalize_k(const float* __restrict__ o3, const int* __restrict__ slotsC,
                           float* __restrict__ dout, int out_size)
{
    const int b = blockIdx.x / 28, oh = blockIdx.x - (blockIdx.x / 28) * 28;
    const float a3 = fmaxf(slot_max(slotsC) / 1023.f, 1e-8f);
    __shared__ float tile[28 * 257];
    const float* src = o3 + (size_t)(b * 28 + oh) * 28 * 256;
    for (int i = threadIdx.x; i < 7168; i += 256)
        tile[(i >> 8) * 257 + (i & 255)] = src[i];
    __syncthreads();
    for (int j = threadIdx.x; j < 7168; j += 256) {
        int c = j / 28, ww = j - (j / 28) * 28;
        float v = tile[ww * 257 + c];
        float q = fminf(rintf(v / a3), 1023.f);
        dout[(((size_t)b * 256 + c) * 28 + oh) * 28 + ww] = q * a3;
    }
    if (blockIdx.x == 0 && threadIdx.x == 0) dout[(size_t)out_size - 1] = a3;
}

// ---------------------------------------------------------------------------
extern "C" void kernel_launch(void* const* d_in, const int* in_sizes, int n_in,
                              void* d_out, int out_size, void* d_ws, size_t ws_size,
                              hipStream_t stream)
{
    const float* x   = (const float*)d_in[0];
    const float* as_ = (const float*)d_in[1];
    const float* wsc = (const float*)d_in[2];
    const float* w1  = (const float*)d_in[3];
    const float* g1  = (const float*)d_in[4];
    const float* b1  = (const float*)d_in[5];
    const float* m1  = (const float*)d_in[6];
    const float* v1  = (const float*)d_in[7];
    const float* w2  = (const float*)d_in[8];
    const float* g2  = (const float*)d_in[9];
    const float* b2  = (const float*)d_in[10];
    const float* m2  = (const float*)d_in[11];
    const float* v2  = (const float*)d_in[12];
    float* out = (float*)d_out;

    char* w = (char*)d_ws;
    size_t off = 0;
    auto alloc = [&](size_t bytes) { size_t c = off; off += (bytes + 255) & ~(size_t)255; return c; };
    const size_t oXF = alloc((size_t)64 * 56 * 56 * 256 * 2);  // hi/lo NHWC fp16 (102.8MB)
    const size_t oY1 = alloc((size_t)NEL * 4);                 // t1 / out3 (51.4MB)
    const size_t oSH = alloc((size_t)NEL * 4);                 // shortcut (51.4MB)
    const size_t oX2 = alloc((size_t)NEL * 2);                 // x2 fp16 (25.7MB)
    const size_t oW1 = alloc((size_t)256 * 2304 * 2);
    const size_t oW2 = alloc((size_t)256 * 2304 * 2);
    const size_t oWS = alloc((size_t)256 * 256 * 2);
    const size_t oSC = alloc((size_t)8 * 256 * 4);
    const size_t oMS = alloc(3 * NSLOT * SLOTSTRIDE * 4 + 2048);
    if (off > ws_size) {
        fprintf(stderr, "kernel_launch: ws too small: need %zu have %zu\n", off, ws_size);
        return;
    }

    _Float16* xf   = (_Float16*)(w + oXF);
    float*    y1   = (float*)(w + oY1);
    float*    sh   = (float*)(w + oSH);
    _Float16* x2   = (_Float16*)(w + oX2);
    _Float16* wq1  = (_Float16*)(w + oW1);
    _Float16* wq2  = (_Float16*)(w + oW2);
    _Float16* wscd = (_Float16*)(w + oWS);
    float* scl = (float*)(w + oSC);
    float *scale1 = scl, *bias1 = scl + 256, *scale_sc = scl + 512, *ws2 = scl + 768,
          *b2f = scl + 1024, *scale2 = scl + 1280, *bias2 = scl + 1536, *a1p = scl + 1792;
    int* slots  = (int*)(w + oMS);
    int* slotsA = slots;
    int* slotsB = slots + NSLOT * SLOTSTRIDE;
    int* slotsC = slots + 2 * NSLOT * SLOTSTRIDE;
    _Float16* zp = (_Float16*)(w + oMS + 3 * NSLOT * SLOTSTRIDE * 4);
    float* y2 = (float*)(w + oXF);   // reuse xf region (dead after conv1)
    float* o3 = (float*)(w + oY1);   // reuse t1 region (dead after quant_x2)

    init_ws<<<1, 256, 0, stream>>>(slots, zp);
    prep_wsc<<<256, 256, 0, stream>>>(wsc, as_, wscd, scale_sc);
    prep_w1<<<256, 256, 0, stream>>>(w1, g1, b1, m1, v1, as_, wq1, scale1, bias1);
    prep_w2<<<256, 256, 0, stream>>>(w2, g2, b2, m2, v2, wq2, ws2, b2f);
    prep_x<<<64 * 56, 256, 0, stream>>>(x, as_, xf);
    conv_k<56, 56, 2, true><<<dim3(392, 2), 256, 0, stream>>>(
        xf, wq1, wscd, scale1, bias1, scale_sc, y1, sh, slotsA, zp);
    mid_k<<<1, 256, 0, stream>>>(slotsA, ws2, b2f, scale2, bias2, a1p);
    quant_x2<<<12544, 256, 0, stream>>>(y1, a1p, x2);
    conv_k<28, 28, 1, false><<<dim3(392, 2), 256, 0, stream>>>(
        x2, wq2, nullptr, scale2, bias2, nullptr, y2, nullptr, slotsB, zp);
    add_short_k<<<3136, 256, 0, stream>>>(y2, sh, slotsB, slotsC, o3);
    finalize_k<<<64 * 28, 256, 0, stream>>>(o3, slotsC, out, out_size);
}